// Round 1
// baseline (520.603 us; speedup 1.0000x reference)
//
#include <hip/hip_runtime.h>

// ---------------------------------------------------------------------------
// SimpleBiquadEQ: 10-band peaking-EQ cascade (IIR) over [32,2,262144] fp32.
// Round 4:
//  - pass_v4: single-wave WGs, NO barriers. NT=4 tiles per WG, double-buffered
//    32 KB LDS, staging via global_load_lds(16B) with PRE-SWIZZLED global
//    source + linear LDS dest (same slot mapping c*16+(q^(c&15)) as before,
//    so compute-phase indexing is unchanged). One s_waitcnt vmcnt(0) per tile;
//    stage(t+1) + reg-prefetch of edge/state overlap compute(t).
//    Grid 16x64 = 1024 WGs = 4/CU -> fully resident (LDS allows 5).
//  - scan_fused: Horner(G=8) -> Kogge-Stone(512) -> rewalk in ONE kernel,
//    one 512-thread WG per sequence; gbuf/sbuf eliminated (LDS hand-off),
//    T stays L2-hot between phases. 6 launches -> 4.
//  - setup: unchanged (validated).
// ---------------------------------------------------------------------------

#define B_   32
#define C_   2
#define S_   262144
#define NB   10
#define SEQ  64

#define F_LCH   64          // samples per chunk
#define F_PCH   4096        // chunks per sequence
#define F_G     8           // chunks per scan group
#define F_GRP   512         // groups per sequence
#define F_NPOW  11          // slot0=A^64, slot1=A^256, slot2..10=A^(512*2^s)
#define NT      4           // tiles (64-chunk spans) per pass workgroup

// ws layout (floats) — same as round 3 (gbuf/sbuf regions now unused)
#define F_OFF_POW 1600
#define F_OFF_T   142400            // 1600 + 32*11*400
#define F_TOT     6696000

// ===========================================================================
// setup: coefficients + matrix powers (fused) — unchanged from round 3
// ===========================================================================
__global__ __launch_bounds__(256) void setup_kernel(
    const float* __restrict__ freqs, const float* __restrict__ gains,
    const float* __restrict__ qs, float* __restrict__ coef,
    float* __restrict__ powers) {
  __shared__ float bufA[400], bufB[400];
  __shared__ float cfs[NB * 5];
  const int b = blockIdx.x, tid = threadIdx.x;
  for (int e = tid; e < 400; e += 256) bufA[e] = 0.0f;
  if (tid < NB) {
    int idx = b * NB + tid;
    float f = freqs[idx], g = gains[idx], Q = qs[idx];
    float w0 = 6.28318530717958648f * f / 44100.0f;
    float sw = sinf(w0), cw = cosf(w0);
    float alpha = sw / (2.0f * Q);
    float A = expf(g * 0.05756462732485114f);   // 10^(g/40)
    float aA = alpha * A, adA = alpha / A;
    float inv = 1.0f / (1.0f + adA);
    float c0 = (1.0f + aA) * inv;
    float c1 = -2.0f * cw * inv;
    float c2 = (1.0f - aA) * inv;
    float c3 = 2.0f * cw * inv;      // -a1
    float c4 = -(1.0f - adA) * inv;  // -a2
    cfs[tid*5+0] = c0; cfs[tid*5+1] = c1; cfs[tid*5+2] = c2;
    cfs[tid*5+3] = c3; cfs[tid*5+4] = c4;
    float* o = coef + idx * 5;
    o[0] = c0; o[1] = c1; o[2] = c2; o[3] = c3; o[4] = c4;
  }
  __syncthreads();
  if (tid < 20) {
    int c = tid;
    float rp = 0.0f;
    for (int k = 0; k < NB; k++) {
      float b0 = cfs[k*5+0], b1 = cfs[k*5+1], b2 = cfs[k*5+2];
      float na1 = cfs[k*5+3], na2 = cfs[k*5+4];
      float val = (k > 0) ? b0 * rp : 0.0f;
      if (k > 0) {
        if (c == 2*k-2) val += b1;
        if (c == 2*k-1) val += b2;
      }
      if (c == 2*k)   val += na1;
      if (c == 2*k+1) val += na2;
      bufA[2*k*20 + c] = val;
      rp = val;
      if (c == 2*k) bufA[(2*k+1)*20 + c] = 1.0f;
    }
  }
  __syncthreads();
  float* cur = bufA;
  float* nxt = bufB;
  float* pw = powers + (size_t)b * F_NPOW * 400;
  for (int j = 1; j <= 17; j++) {   // cur becomes A^(2^j)
    for (int e = tid; e < 400; e += 256) {
      int r = e / 20, c = e % 20;
      float acc = 0.0f;
      #pragma unroll
      for (int k = 0; k < 20; k++) acc = fmaf(cur[r*20+k], cur[k*20+c], acc);
      nxt[e] = acc;
    }
    __syncthreads();
    { float* t_ = cur; cur = nxt; nxt = t_; }
    int slot = -1;
    if (j == 6) slot = 0;            // A^64
    else if (j == 8) slot = 1;       // A^256 (layout only)
    else if (j == 9) slot = 2;       // A^512
    else if (j >= 10) slot = j - 7;  // A^1024..A^131072
    if (slot >= 0) for (int e = tid; e < 400; e += 256) pw[slot*400 + e] = cur[e];
  }
}

// ===========================================================================
// pass v4 helpers
// ===========================================================================
__device__ __forceinline__ void stage_tile(const float* xseq, float4* dst,
                                           int tile, int lane) {
  // linear LDS dest (lane l -> slot it*64+l), pre-swizzled global source so
  // slot c*16+qs holds global quad (c, qs^(c&15)) — identical layout to r3.
  const float4* gx = (const float4*)(xseq + (size_t)tile * 4096);
  #pragma unroll
  for (int it = 0; it < 16; it++) {
    const int f = it * 64 + lane;
    const int c = f >> 4;
    const int gi = (c << 4) | ((f & 15) ^ (c & 15));
    __builtin_amdgcn_global_load_lds(
        (const __attribute__((address_space(1))) void*)(gx + gi),
        (__attribute__((address_space(3))) void*)(dst + it * 64),
        16, 0, 0);
  }
}

template <bool WRITE_OUT>
__device__ __forceinline__ void prefetch_es(
    const float* xseq, const float* tst, int seq, int tile, int lane,
    float2& pe, float4 (&pst)[5]) {
  if (tile > 0) {
    const float2* ep = (const float2*)(xseq + (size_t)tile * 4096) - 1;
    pe = *ep;                        // {x[-2], x[-1]} (same addr all lanes)
  } else {
    pe = make_float2(0.f, 0.f);
  }
  if constexpr (WRITE_OUT) {
    const int chunk = tile * F_LCH + lane;
    const int cm1 = chunk > 0 ? chunk - 1 : 0;   // clamp; zeroed later
    const float4* sv = (const float4*)(tst + ((size_t)seq * F_PCH + cm1) * 20);
    #pragma unroll
    for (int i = 0; i < 5; i++) pst[i] = sv[i];
  }
}

// ===========================================================================
// passes: 1 wave per wg, NT tiles pipelined, no barriers.
// ===========================================================================
template <bool WRITE_OUT>
__global__ __launch_bounds__(64) void pass_v4(
    const float* __restrict__ x, const float* __restrict__ coef,
    const float* __restrict__ tst, float* __restrict__ tout,
    float* __restrict__ out) {
  __shared__ float4 lds4[2048];     // 2 x 16 KB double buffer
  const int seq = blockIdx.y;
  const int b = seq >> 1;
  const int lane = threadIdx.x;
  const int tile0 = blockIdx.x * NT;
  const float* cf = coef + b * NB * 5;       // uniform -> scalar loads
  float b0[NB], b1[NB], b2[NB], na1[NB], na2[NB];
  #pragma unroll
  for (int k = 0; k < NB; k++) {
    b0[k] = cf[k*5+0]; b1[k] = cf[k*5+1]; b2[k] = cf[k*5+2];
    na1[k] = cf[k*5+3]; na2[k] = cf[k*5+4];
  }
  const float* xseq = x + (size_t)seq * S_;

  float2 peC = make_float2(0.f, 0.f), peN = make_float2(0.f, 0.f);
  float4 pstC[5] = {}, pstN[5] = {};

  // prologue: stage tile0 into buf0, prefetch its edge/state regs
  stage_tile(xseq, lds4, tile0, lane);
  prefetch_es<WRITE_OUT>(xseq, tst, seq, tile0, lane, peC, pstC);

  #pragma unroll 1
  for (int t = 0; t < NT; t++) {
    const int tile = tile0 + t;
    float4* lbuf = lds4 + ((t & 1) << 10);
    // PF(t) was issued one full compute-phase ago -> wait is cheap.
    // lgkmcnt(0): prior store-phase ds_reads retired before buf reuse.
    asm volatile("s_waitcnt vmcnt(0) lgkmcnt(0)" ::: "memory");
    __builtin_amdgcn_sched_barrier(0);
    if (t + 1 < NT) {   // overlap next tile's staging with this compute
      stage_tile(xseq, lds4 + (((t + 1) & 1) << 10), tile + 1, lane);
      prefetch_es<WRITE_OUT>(xseq, tst, seq, tile + 1, lane, peN, pstN);
    }
    // ---- init state ----
    const int chunk = tile * F_LCH + lane;
    float x1, x2;
    if (lane == 0) {
      x1 = peC.y; x2 = peC.x;       // zeros when tile==0
    } else {
      float4 pv = lbuf[(lane-1)*16 + (15 ^ ((lane-1) & 15))];
      x2 = pv.z; x1 = pv.w;
    }
    float p[NB], q_[NB];
    if (WRITE_OUT) {
      const bool z = (chunk == 0);
      #pragma unroll
      for (int i = 0; i < 5; i++) {
        float4 a = pstC[i];
        p[2*i]   = z ? 0.f : a.x;  q_[2*i]   = z ? 0.f : a.y;
        p[2*i+1] = z ? 0.f : a.z;  q_[2*i+1] = z ? 0.f : a.w;
      }
    } else {
      #pragma unroll
      for (int k = 0; k < NB; k++) { p[k] = 0.0f; q_[k] = 0.0f; }
    }
    // ---- compute: my chunk = lane, 16 float4 from LDS ----
    #pragma unroll 2
    for (int qq = 0; qq < 16; qq++) {
      const int slot = lane*16 + (qq ^ (lane & 15));
      float4 xv = lbuf[slot];
      float xin[4] = {xv.x, xv.y, xv.z, xv.w};
      float o[4];
      #pragma unroll
      for (int j = 0; j < 4; j++) {
        float u = xin[j], u1 = x1, u2 = x2;
        x2 = x1; x1 = xin[j];
        #pragma unroll
        for (int k = 0; k < NB; k++) {
          float v = fmaf(b0[k], u,
                    fmaf(b1[k], u1,
                    fmaf(b2[k], u2,
                    fmaf(na1[k], p[k], na2[k] * q_[k]))));
          u1 = p[k]; u2 = q_[k];
          q_[k] = p[k]; p[k] = v;
          u = v;
        }
        o[j] = u;
      }
      if (WRITE_OUT) lbuf[slot] = make_float4(o[0], o[1], o[2], o[3]);
    }
    if (WRITE_OUT) {
      asm volatile("" ::: "memory");   // keep ds_writes before store-phase reads
      float4* gy = (float4*)(out + (size_t)seq * S_ + (size_t)tile * 4096);
      #pragma unroll 4
      for (int it = 0; it < 16; it++) {
        int f = it * 64 + lane;
        int c = f >> 4, q = f & 15;
        gy[f] = lbuf[c*16 + (q ^ (c & 15))];
      }
    } else {
      float4* td = (float4*)(tout + ((size_t)seq * F_PCH + chunk) * 20);
      #pragma unroll
      for (int i = 0; i < 5; i++)
        td[i] = make_float4(p[2*i], q_[2*i], p[2*i+1], q_[2*i+1]);
    }
    peC = peN;
    #pragma unroll
    for (int i = 0; i < 5; i++) pstC[i] = pstN[i];
  }
}

// ===========================================================================
// fused scan: Horner (no writeback) -> Kogge-Stone -> rewalk (writeback).
// One 512-thread WG per sequence; group totals hand off through LDS.
// ===========================================================================
__device__ __forceinline__ void matvec_acc(const float* M /*[c*20+r]*/,
                                           const float* v, float* acc) {
  #pragma unroll
  for (int c = 0; c < 20; c++) {
    float vc = v[c];
    const float4* col = (const float4*)&M[c*20];
    float4 c0 = col[0], c1 = col[1], c2 = col[2], c3 = col[3], c4 = col[4];
    acc[0]  = fmaf(c0.x, vc, acc[0]);  acc[1]  = fmaf(c0.y, vc, acc[1]);
    acc[2]  = fmaf(c0.z, vc, acc[2]);  acc[3]  = fmaf(c0.w, vc, acc[3]);
    acc[4]  = fmaf(c1.x, vc, acc[4]);  acc[5]  = fmaf(c1.y, vc, acc[5]);
    acc[6]  = fmaf(c1.z, vc, acc[6]);  acc[7]  = fmaf(c1.w, vc, acc[7]);
    acc[8]  = fmaf(c2.x, vc, acc[8]);  acc[9]  = fmaf(c2.y, vc, acc[9]);
    acc[10] = fmaf(c2.z, vc, acc[10]); acc[11] = fmaf(c2.w, vc, acc[11]);
    acc[12] = fmaf(c3.x, vc, acc[12]); acc[13] = fmaf(c3.y, vc, acc[13]);
    acc[14] = fmaf(c3.z, vc, acc[14]); acc[15] = fmaf(c3.w, vc, acc[15]);
    acc[16] = fmaf(c4.x, vc, acc[16]); acc[17] = fmaf(c4.y, vc, acc[17]);
    acc[18] = fmaf(c4.z, vc, acc[18]); acc[19] = fmaf(c4.w, vc, acc[19]);
  }
}

__global__ __launch_bounds__(512) void scan_fused(
    float* __restrict__ t, const float* __restrict__ powers) {
  __shared__ float h[F_GRP * 20];   // 40 KB
  __shared__ float Msh[400];        // transposed A^64
  __shared__ float Ksh[400];        // transposed KS step matrix
  const int seq = blockIdx.x, b = seq >> 1;
  const int g = threadIdx.x;        // group 0..511
  const float* pw0 = powers + (size_t)b * F_NPOW * 400;
  for (int e = g; e < 400; e += 512) {
    int r = e / 20, c = e % 20;
    Msh[c*20 + r] = pw0[e];
  }
  __syncthreads();
  // ---- phase 1: per-group Horner totals (zero init, no writeback) ----
  float s[20];
  #pragma unroll
  for (int r = 0; r < 20; r++) s[r] = 0.0f;
  float* tp = t + ((size_t)seq * F_PCH + (size_t)g * F_G) * 20;
  const float4* tv = (const float4*)tp;
  float4 nx[5];
  #pragma unroll
  for (int i = 0; i < 5; i++) nx[i] = tv[i];
  #pragma unroll 1
  for (int j = 0; j < F_G; j++) {
    float ns[20];
    #pragma unroll
    for (int i = 0; i < 5; i++) {
      float4 a = nx[i];
      ns[4*i] = a.x; ns[4*i+1] = a.y; ns[4*i+2] = a.z; ns[4*i+3] = a.w;
    }
    if (j < F_G - 1) {
      #pragma unroll
      for (int i = 0; i < 5; i++) nx[i] = tv[(j+1)*5 + i];
    }
    matvec_acc(Msh, s, ns);
    #pragma unroll
    for (int r = 0; r < 20; r++) s[r] = ns[r];
  }
  #pragma unroll
  for (int r = 0; r < 20; r++) h[g*20 + r] = s[r];
  // ---- phase 2: Kogge-Stone over 512 totals ----
  for (int st = 0; st < 9; st++) {
    const int d = 1 << st;
    const float* pwS = pw0 + (size_t)(2 + st) * 400;   // A^(512*2^st)
    __syncthreads();
    for (int e = g; e < 400; e += 512) {
      int r = e / 20, c = e % 20;
      Ksh[c*20 + r] = pwS[e];
    }
    float nb[20];
    if (g >= d) {
      const float4* hv = (const float4*)&h[(g - d) * 20];
      #pragma unroll
      for (int k = 0; k < 5; k++) {
        float4 a = hv[k];
        nb[4*k] = a.x; nb[4*k+1] = a.y; nb[4*k+2] = a.z; nb[4*k+3] = a.w;
      }
    }
    __syncthreads();
    if (g >= d) {
      matvec_acc(Ksh, nb, s);
      #pragma unroll
      for (int r = 0; r < 20; r++) h[g*20 + r] = s[r];
    }
  }
  __syncthreads();
  // ---- exclusive shift (from LDS, no sbuf round trip) ----
  float sx[20];
  if (g > 0) {
    const float4* hv = (const float4*)&h[(g - 1) * 20];
    #pragma unroll
    for (int k = 0; k < 5; k++) {
      float4 a = hv[k];
      sx[4*k] = a.x; sx[4*k+1] = a.y; sx[4*k+2] = a.z; sx[4*k+3] = a.w;
    }
  } else {
    #pragma unroll
    for (int r = 0; r < 20; r++) sx[r] = 0.0f;
  }
  // ---- phase 3: rewalk with writeback (T still L2-hot) ----
  #pragma unroll
  for (int i = 0; i < 5; i++) nx[i] = tv[i];
  #pragma unroll
  for (int r = 0; r < 20; r++) s[r] = sx[r];
  #pragma unroll 1
  for (int j = 0; j < F_G; j++) {
    float ns[20];
    #pragma unroll
    for (int i = 0; i < 5; i++) {
      float4 a = nx[i];
      ns[4*i] = a.x; ns[4*i+1] = a.y; ns[4*i+2] = a.z; ns[4*i+3] = a.w;
    }
    if (j < F_G - 1) {
      #pragma unroll
      for (int i = 0; i < 5; i++) nx[i] = tv[(j+1)*5 + i];
    }
    matvec_acc(Msh, s, ns);
    #pragma unroll
    for (int r = 0; r < 20; r++) s[r] = ns[r];
    float4* tw = (float4*)(tp + j * 20);
    #pragma unroll
    for (int i = 0; i < 5; i++)
      tw[i] = make_float4(s[4*i], s[4*i+1], s[4*i+2], s[4*i+3]);
  }
}

// ===========================================================================
extern "C" void kernel_launch(void* const* d_in, const int* in_sizes, int n_in,
                              void* d_out, int out_size, void* d_ws, size_t ws_size,
                              hipStream_t stream) {
  const float* audio = (const float*)d_in[0];
  const float* freqs = (const float*)d_in[1];
  const float* gains = (const float*)d_in[2];
  const float* qs    = (const float*)d_in[3];
  float* out = (float*)d_out;
  float* ws  = (float*)d_ws;
  float* coef   = ws;
  float* powers = ws + F_OFF_POW;
  float* t      = ws + F_OFF_T;

  hipLaunchKernelGGL(setup_kernel, dim3(B_), dim3(256), 0, stream,
                     freqs, gains, qs, coef, powers);
  hipLaunchKernelGGL((pass_v4<false>), dim3(64 / NT, SEQ), dim3(64), 0, stream,
                     audio, coef, (const float*)nullptr, t, (float*)nullptr);
  hipLaunchKernelGGL(scan_fused, dim3(SEQ), dim3(512), 0, stream,
                     t, powers);
  hipLaunchKernelGGL((pass_v4<true>), dim3(64 / NT, SEQ), dim3(64), 0, stream,
                     audio, coef, t, (float*)nullptr, out);
}

// Round 2
// 490.089 us; speedup vs baseline: 1.0623x; 1.0623x over previous
//
#include <hip/hip_runtime.h>

// ---------------------------------------------------------------------------
// SimpleBiquadEQ: 10-band peaking-EQ cascade (IIR) over [32,2,262144] fp32.
// Round 5:
//  - T LAYOUT TRANSPOSED (the round-4 regression fix): chunk-state tensor is
//    now T[seq][j=chunk&7][i=0..4(float4)][g=chunk>>3], planes of 512 float4.
//    scan_fused's Horner/rewalk step j reads lanes g,g+1,... as CONSECUTIVE
//    float4s (perfectly coalesced; was 64 scattered lines -> 201 MB fetch,
//    757 GB/s latency-bound). Pass writer/reader see 128B contiguous runs.
//  - scan_fused: same validated 3-phase math (Horner G=8 / KS 512 / rewalk),
//    only addressing changed.
//  - pass_v4: unchanged except T addressing in state write / state prefetch.
//  - setup: unchanged (validated).
// ---------------------------------------------------------------------------

#define B_   32
#define C_   2
#define S_   262144
#define NB   10
#define SEQ  64

#define F_LCH   64          // samples per chunk
#define F_PCH   4096        // chunks per sequence
#define F_G     8           // chunks per scan group
#define F_GRP   512         // groups per sequence
#define F_NPOW  11          // slot0=A^64, slot1=A^256, slot2..10=A^(512*2^s)
#define NT      4           // tiles (64-chunk spans) per pass workgroup

// ws layout (floats)
#define F_OFF_POW 1600
#define F_OFF_T   142400            // 1600 + 32*11*400
#define F_TOT     6696000

// T addressing (float4 units): plane(seq,j,i) = ((seq*8 + j)*5 + i)*512, + g
// where chunk = 8*g + j. Per seq: 40 planes x 512 float4 = 81920 floats.

// ===========================================================================
// setup: coefficients + matrix powers (fused) — unchanged
// ===========================================================================
__global__ __launch_bounds__(256) void setup_kernel(
    const float* __restrict__ freqs, const float* __restrict__ gains,
    const float* __restrict__ qs, float* __restrict__ coef,
    float* __restrict__ powers) {
  __shared__ float bufA[400], bufB[400];
  __shared__ float cfs[NB * 5];
  const int b = blockIdx.x, tid = threadIdx.x;
  for (int e = tid; e < 400; e += 256) bufA[e] = 0.0f;
  if (tid < NB) {
    int idx = b * NB + tid;
    float f = freqs[idx], g = gains[idx], Q = qs[idx];
    float w0 = 6.28318530717958648f * f / 44100.0f;
    float sw = sinf(w0), cw = cosf(w0);
    float alpha = sw / (2.0f * Q);
    float A = expf(g * 0.05756462732485114f);   // 10^(g/40)
    float aA = alpha * A, adA = alpha / A;
    float inv = 1.0f / (1.0f + adA);
    float c0 = (1.0f + aA) * inv;
    float c1 = -2.0f * cw * inv;
    float c2 = (1.0f - aA) * inv;
    float c3 = 2.0f * cw * inv;      // -a1
    float c4 = -(1.0f - adA) * inv;  // -a2
    cfs[tid*5+0] = c0; cfs[tid*5+1] = c1; cfs[tid*5+2] = c2;
    cfs[tid*5+3] = c3; cfs[tid*5+4] = c4;
    float* o = coef + idx * 5;
    o[0] = c0; o[1] = c1; o[2] = c2; o[3] = c3; o[4] = c4;
  }
  __syncthreads();
  if (tid < 20) {
    int c = tid;
    float rp = 0.0f;
    for (int k = 0; k < NB; k++) {
      float b0 = cfs[k*5+0], b1 = cfs[k*5+1], b2 = cfs[k*5+2];
      float na1 = cfs[k*5+3], na2 = cfs[k*5+4];
      float val = (k > 0) ? b0 * rp : 0.0f;
      if (k > 0) {
        if (c == 2*k-2) val += b1;
        if (c == 2*k-1) val += b2;
      }
      if (c == 2*k)   val += na1;
      if (c == 2*k+1) val += na2;
      bufA[2*k*20 + c] = val;
      rp = val;
      if (c == 2*k) bufA[(2*k+1)*20 + c] = 1.0f;
    }
  }
  __syncthreads();
  float* cur = bufA;
  float* nxt = bufB;
  float* pw = powers + (size_t)b * F_NPOW * 400;
  for (int j = 1; j <= 17; j++) {   // cur becomes A^(2^j)
    for (int e = tid; e < 400; e += 256) {
      int r = e / 20, c = e % 20;
      float acc = 0.0f;
      #pragma unroll
      for (int k = 0; k < 20; k++) acc = fmaf(cur[r*20+k], cur[k*20+c], acc);
      nxt[e] = acc;
    }
    __syncthreads();
    { float* t_ = cur; cur = nxt; nxt = t_; }
    int slot = -1;
    if (j == 6) slot = 0;            // A^64
    else if (j == 8) slot = 1;       // A^256 (layout only)
    else if (j == 9) slot = 2;       // A^512
    else if (j >= 10) slot = j - 7;  // A^1024..A^131072
    if (slot >= 0) for (int e = tid; e < 400; e += 256) pw[slot*400 + e] = cur[e];
  }
}

// ===========================================================================
// pass v4 helpers
// ===========================================================================
__device__ __forceinline__ void stage_tile(const float* xseq, float4* dst,
                                           int tile, int lane) {
  // linear LDS dest (lane l -> slot it*64+l), pre-swizzled global source so
  // slot c*16+qs holds global quad (c, qs^(c&15)).
  const float4* gx = (const float4*)(xseq + (size_t)tile * 4096);
  #pragma unroll
  for (int it = 0; it < 16; it++) {
    const int f = it * 64 + lane;
    const int c = f >> 4;
    const int gi = (c << 4) | ((f & 15) ^ (c & 15));
    __builtin_amdgcn_global_load_lds(
        (const __attribute__((address_space(1))) void*)(gx + gi),
        (__attribute__((address_space(3))) void*)(dst + it * 64),
        16, 0, 0);
  }
}

template <bool WRITE_OUT>
__device__ __forceinline__ void prefetch_es(
    const float* xseq, const float* tst, int seq, int tile, int lane,
    float2& pe, float4 (&pst)[5]) {
  if (tile > 0) {
    const float2* ep = (const float2*)(xseq + (size_t)tile * 4096) - 1;
    pe = *ep;                        // {x[-2], x[-1]} (same addr all lanes)
  } else {
    pe = make_float2(0.f, 0.f);
  }
  if constexpr (WRITE_OUT) {
    const int chunk = tile * F_LCH + lane;
    const int cm1 = chunk > 0 ? chunk - 1 : 0;   // clamp; zeroed later
    const int jj = cm1 & 7, gg = cm1 >> 3;
    const float4* sv = (const float4*)tst +
                       (((size_t)seq * 8 + jj) * 5) * 512 + gg;
    #pragma unroll
    for (int i = 0; i < 5; i++) pst[i] = sv[i * 512];
  }
}

// ===========================================================================
// passes: 1 wave per wg, NT tiles pipelined, no barriers.
// ===========================================================================
template <bool WRITE_OUT>
__global__ __launch_bounds__(64) void pass_v4(
    const float* __restrict__ x, const float* __restrict__ coef,
    const float* __restrict__ tst, float* __restrict__ tout,
    float* __restrict__ out) {
  __shared__ float4 lds4[2048];     // 2 x 16 KB double buffer
  const int seq = blockIdx.y;
  const int b = seq >> 1;
  const int lane = threadIdx.x;
  const int tile0 = blockIdx.x * NT;
  const float* cf = coef + b * NB * 5;       // uniform -> scalar loads
  float b0[NB], b1[NB], b2[NB], na1[NB], na2[NB];
  #pragma unroll
  for (int k = 0; k < NB; k++) {
    b0[k] = cf[k*5+0]; b1[k] = cf[k*5+1]; b2[k] = cf[k*5+2];
    na1[k] = cf[k*5+3]; na2[k] = cf[k*5+4];
  }
  const float* xseq = x + (size_t)seq * S_;

  float2 peC = make_float2(0.f, 0.f), peN = make_float2(0.f, 0.f);
  float4 pstC[5] = {}, pstN[5] = {};

  // prologue: stage tile0 into buf0, prefetch its edge/state regs
  stage_tile(xseq, lds4, tile0, lane);
  prefetch_es<WRITE_OUT>(xseq, tst, seq, tile0, lane, peC, pstC);

  #pragma unroll 1
  for (int t = 0; t < NT; t++) {
    const int tile = tile0 + t;
    float4* lbuf = lds4 + ((t & 1) << 10);
    asm volatile("s_waitcnt vmcnt(0) lgkmcnt(0)" ::: "memory");
    __builtin_amdgcn_sched_barrier(0);
    if (t + 1 < NT) {   // overlap next tile's staging with this compute
      stage_tile(xseq, lds4 + (((t + 1) & 1) << 10), tile + 1, lane);
      prefetch_es<WRITE_OUT>(xseq, tst, seq, tile + 1, lane, peN, pstN);
    }
    // ---- init state ----
    const int chunk = tile * F_LCH + lane;
    float x1, x2;
    if (lane == 0) {
      x1 = peC.y; x2 = peC.x;       // zeros when tile==0
    } else {
      float4 pv = lbuf[(lane-1)*16 + (15 ^ ((lane-1) & 15))];
      x2 = pv.z; x1 = pv.w;
    }
    float p[NB], q_[NB];
    if (WRITE_OUT) {
      const bool z = (chunk == 0);
      #pragma unroll
      for (int i = 0; i < 5; i++) {
        float4 a = pstC[i];
        p[2*i]   = z ? 0.f : a.x;  q_[2*i]   = z ? 0.f : a.y;
        p[2*i+1] = z ? 0.f : a.z;  q_[2*i+1] = z ? 0.f : a.w;
      }
    } else {
      #pragma unroll
      for (int k = 0; k < NB; k++) { p[k] = 0.0f; q_[k] = 0.0f; }
    }
    // ---- compute: my chunk = lane, 16 float4 from LDS ----
    #pragma unroll 2
    for (int qq = 0; qq < 16; qq++) {
      const int slot = lane*16 + (qq ^ (lane & 15));
      float4 xv = lbuf[slot];
      float xin[4] = {xv.x, xv.y, xv.z, xv.w};
      float o[4];
      #pragma unroll
      for (int j = 0; j < 4; j++) {
        float u = xin[j], u1 = x1, u2 = x2;
        x2 = x1; x1 = xin[j];
        #pragma unroll
        for (int k = 0; k < NB; k++) {
          float v = fmaf(b0[k], u,
                    fmaf(b1[k], u1,
                    fmaf(b2[k], u2,
                    fmaf(na1[k], p[k], na2[k] * q_[k]))));
          u1 = p[k]; u2 = q_[k];
          q_[k] = p[k]; p[k] = v;
          u = v;
        }
        o[j] = u;
      }
      if (WRITE_OUT) lbuf[slot] = make_float4(o[0], o[1], o[2], o[3]);
    }
    if (WRITE_OUT) {
      asm volatile("" ::: "memory");   // keep ds_writes before store-phase reads
      float4* gy = (float4*)(out + (size_t)seq * S_ + (size_t)tile * 4096);
      #pragma unroll 4
      for (int it = 0; it < 16; it++) {
        int f = it * 64 + lane;
        int c = f >> 4, q = f & 15;
        gy[f] = lbuf[c*16 + (q ^ (c & 15))];
      }
    } else {
      // transposed T write: plane-major, lanes land in 128B contiguous runs
      const int jj = chunk & 7, gg = chunk >> 3;
      float4* td = (float4*)tout + (((size_t)seq * 8 + jj) * 5) * 512 + gg;
      td[0]    = make_float4(p[0], q_[0], p[1], q_[1]);
      td[512]  = make_float4(p[2], q_[2], p[3], q_[3]);
      td[1024] = make_float4(p[4], q_[4], p[5], q_[5]);
      td[1536] = make_float4(p[6], q_[6], p[7], q_[7]);
      td[2048] = make_float4(p[8], q_[8], p[9], q_[9]);
    }
    peC = peN;
    #pragma unroll
    for (int i = 0; i < 5; i++) pstC[i] = pstN[i];
  }
}

// ===========================================================================
// fused scan: Horner (no writeback) -> Kogge-Stone -> rewalk (writeback).
// One 512-thread WG per sequence; group totals hand off through LDS.
// T reads/writes now perfectly coalesced (lane g -> float4 g of plane j,i).
// ===========================================================================
__device__ __forceinline__ void matvec_acc(const float* M /*[c*20+r]*/,
                                           const float* v, float* acc) {
  #pragma unroll
  for (int c = 0; c < 20; c++) {
    float vc = v[c];
    const float4* col = (const float4*)&M[c*20];
    float4 c0 = col[0], c1 = col[1], c2 = col[2], c3 = col[3], c4 = col[4];
    acc[0]  = fmaf(c0.x, vc, acc[0]);  acc[1]  = fmaf(c0.y, vc, acc[1]);
    acc[2]  = fmaf(c0.z, vc, acc[2]);  acc[3]  = fmaf(c0.w, vc, acc[3]);
    acc[4]  = fmaf(c1.x, vc, acc[4]);  acc[5]  = fmaf(c1.y, vc, acc[5]);
    acc[6]  = fmaf(c1.z, vc, acc[6]);  acc[7]  = fmaf(c1.w, vc, acc[7]);
    acc[8]  = fmaf(c2.x, vc, acc[8]);  acc[9]  = fmaf(c2.y, vc, acc[9]);
    acc[10] = fmaf(c2.z, vc, acc[10]); acc[11] = fmaf(c2.w, vc, acc[11]);
    acc[12] = fmaf(c3.x, vc, acc[12]); acc[13] = fmaf(c3.y, vc, acc[13]);
    acc[14] = fmaf(c3.z, vc, acc[14]); acc[15] = fmaf(c3.w, vc, acc[15]);
    acc[16] = fmaf(c4.x, vc, acc[16]); acc[17] = fmaf(c4.y, vc, acc[17]);
    acc[18] = fmaf(c4.z, vc, acc[18]); acc[19] = fmaf(c4.w, vc, acc[19]);
  }
}

__global__ __launch_bounds__(512) void scan_fused(
    float* __restrict__ t, const float* __restrict__ powers) {
  __shared__ float h[F_GRP * 20];   // 40 KB
  __shared__ float Msh[400];        // transposed A^64
  __shared__ float Ksh[400];        // transposed KS step matrix
  const int seq = blockIdx.x, b = seq >> 1;
  const int g = threadIdx.x;        // group 0..511
  const float* pw0 = powers + (size_t)b * F_NPOW * 400;
  for (int e = g; e < 400; e += 512) {
    int r = e / 20, c = e % 20;
    Msh[c*20 + r] = pw0[e];
  }
  __syncthreads();
  // T base for this thread: float4 g of plane (seq, j, i)
  const float4* tb = (const float4*)t + (size_t)seq * 40 * 512 + g;
  // ---- phase 1: per-group Horner totals (zero init, no writeback) ----
  float s[20];
  #pragma unroll
  for (int r = 0; r < 20; r++) s[r] = 0.0f;
  float4 nx[5];
  #pragma unroll
  for (int i = 0; i < 5; i++) nx[i] = tb[i * 512];        // j=0
  #pragma unroll 1
  for (int j = 0; j < F_G; j++) {
    float ns[20];
    #pragma unroll
    for (int i = 0; i < 5; i++) {
      float4 a = nx[i];
      ns[4*i] = a.x; ns[4*i+1] = a.y; ns[4*i+2] = a.z; ns[4*i+3] = a.w;
    }
    if (j < F_G - 1) {
      const float4* np = tb + (size_t)(j + 1) * 5 * 512;
      #pragma unroll
      for (int i = 0; i < 5; i++) nx[i] = np[i * 512];
    }
    matvec_acc(Msh, s, ns);
    #pragma unroll
    for (int r = 0; r < 20; r++) s[r] = ns[r];
  }
  #pragma unroll
  for (int r = 0; r < 20; r++) h[g*20 + r] = s[r];
  // ---- phase 2: Kogge-Stone over 512 totals ----
  for (int st = 0; st < 9; st++) {
    const int d = 1 << st;
    const float* pwS = pw0 + (size_t)(2 + st) * 400;   // A^(512*2^st)
    __syncthreads();
    for (int e = g; e < 400; e += 512) {
      int r = e / 20, c = e % 20;
      Ksh[c*20 + r] = pwS[e];
    }
    float nb[20];
    if (g >= d) {
      const float4* hv = (const float4*)&h[(g - d) * 20];
      #pragma unroll
      for (int k = 0; k < 5; k++) {
        float4 a = hv[k];
        nb[4*k] = a.x; nb[4*k+1] = a.y; nb[4*k+2] = a.z; nb[4*k+3] = a.w;
      }
    }
    __syncthreads();
    if (g >= d) {
      matvec_acc(Ksh, nb, s);
      #pragma unroll
      for (int r = 0; r < 20; r++) h[g*20 + r] = s[r];
    }
  }
  __syncthreads();
  // ---- exclusive shift (from LDS) ----
  float sx[20];
  if (g > 0) {
    const float4* hv = (const float4*)&h[(g - 1) * 20];
    #pragma unroll
    for (int k = 0; k < 5; k++) {
      float4 a = hv[k];
      sx[4*k] = a.x; sx[4*k+1] = a.y; sx[4*k+2] = a.z; sx[4*k+3] = a.w;
    }
  } else {
    #pragma unroll
    for (int r = 0; r < 20; r++) sx[r] = 0.0f;
  }
  // ---- phase 3: rewalk with writeback (T L2/L3-hot) ----
  float4* tw = (float4*)t + (size_t)seq * 40 * 512 + g;
  #pragma unroll
  for (int i = 0; i < 5; i++) nx[i] = tb[i * 512];
  #pragma unroll
  for (int r = 0; r < 20; r++) s[r] = sx[r];
  #pragma unroll 1
  for (int j = 0; j < F_G; j++) {
    float ns[20];
    #pragma unroll
    for (int i = 0; i < 5; i++) {
      float4 a = nx[i];
      ns[4*i] = a.x; ns[4*i+1] = a.y; ns[4*i+2] = a.z; ns[4*i+3] = a.w;
    }
    if (j < F_G - 1) {
      const float4* np = tb + (size_t)(j + 1) * 5 * 512;
      #pragma unroll
      for (int i = 0; i < 5; i++) nx[i] = np[i * 512];
    }
    matvec_acc(Msh, s, ns);
    #pragma unroll
    for (int r = 0; r < 20; r++) s[r] = ns[r];
    float4* wp = tw + (size_t)j * 5 * 512;
    wp[0]    = make_float4(s[0],  s[1],  s[2],  s[3]);
    wp[512]  = make_float4(s[4],  s[5],  s[6],  s[7]);
    wp[1024] = make_float4(s[8],  s[9],  s[10], s[11]);
    wp[1536] = make_float4(s[12], s[13], s[14], s[15]);
    wp[2048] = make_float4(s[16], s[17], s[18], s[19]);
  }
}

// ===========================================================================
extern "C" void kernel_launch(void* const* d_in, const int* in_sizes, int n_in,
                              void* d_out, int out_size, void* d_ws, size_t ws_size,
                              hipStream_t stream) {
  const float* audio = (const float*)d_in[0];
  const float* freqs = (const float*)d_in[1];
  const float* gains = (const float*)d_in[2];
  const float* qs    = (const float*)d_in[3];
  float* out = (float*)d_out;
  float* ws  = (float*)d_ws;
  float* coef   = ws;
  float* powers = ws + F_OFF_POW;
  float* t      = ws + F_OFF_T;

  hipLaunchKernelGGL(setup_kernel, dim3(B_), dim3(256), 0, stream,
                     freqs, gains, qs, coef, powers);
  hipLaunchKernelGGL((pass_v4<false>), dim3(64 / NT, SEQ), dim3(64), 0, stream,
                     audio, coef, (const float*)nullptr, t, (float*)nullptr);
  hipLaunchKernelGGL(scan_fused, dim3(SEQ), dim3(512), 0, stream,
                     t, powers);
  hipLaunchKernelGGL((pass_v4<true>), dim3(64 / NT, SEQ), dim3(64), 0, stream,
                     audio, coef, t, (float*)nullptr, out);
}

// Round 3
// 265.644 us; speedup vs baseline: 1.9598x; 1.8449x over previous
//
#include <hip/hip_runtime.h>

// ---------------------------------------------------------------------------
// SimpleBiquadEQ: 10-band peaking-EQ cascade (IIR) over [32,2,262144] fp32.
// Round 6:
//  - UN-FUSE the scan (round-5 regression root cause: 512-thread fused kernel
//    hit the 128-VGPR launch_bounds cap -> scratch spills -> latency-bound at
//    VALUBusy 1.5%, plus only 64 WGs of dispatch parallelism).
//    Back to validated 3-kernel scan (Horner / KS / rewalk) BUT:
//      * keep the transposed T layout (coalesced plane reads — the r5 win)
//      * scan_horner now 128-thread WGs, grid 4x64 = 256 WGs (all CUs),
//        VGPR cap 256 -> no spills.
//      * scan_ks verbatim from validated round 3.
//  - pass_v4 unchanged (single-wave pipelined, global_load_lds staging).
//  - setup unchanged.
// ---------------------------------------------------------------------------

#define B_   32
#define C_   2
#define S_   262144
#define NB   10
#define SEQ  64

#define F_LCH   64          // samples per chunk
#define F_PCH   4096        // chunks per sequence
#define F_G     8           // chunks per scan group
#define F_GRP   512         // groups per sequence
#define F_NPOW  11          // slot0=A^64, slot1=A^256, slot2..10=A^(512*2^s)
#define NT      4           // tiles (64-chunk spans) per pass workgroup

// ws layout (floats)
#define F_OFF_POW 1600
#define F_OFF_T   142400            // 1600 + 32*11*400
#define F_OFF_G   5385280           // + 64*4096*20
#define F_OFF_SB  6040640           // + 64*512*20
#define F_TOT     6696000           // 26.78 MB (same footprint as round 3)

// T addressing (float4 units): plane(seq,j,i) = ((seq*8 + j)*5 + i)*512, + g
// where chunk = 8*g + j. Per seq: 40 planes x 512 float4 = 81920 floats.

// ===========================================================================
// setup: coefficients + matrix powers (fused) — unchanged
// ===========================================================================
__global__ __launch_bounds__(256) void setup_kernel(
    const float* __restrict__ freqs, const float* __restrict__ gains,
    const float* __restrict__ qs, float* __restrict__ coef,
    float* __restrict__ powers) {
  __shared__ float bufA[400], bufB[400];
  __shared__ float cfs[NB * 5];
  const int b = blockIdx.x, tid = threadIdx.x;
  for (int e = tid; e < 400; e += 256) bufA[e] = 0.0f;
  if (tid < NB) {
    int idx = b * NB + tid;
    float f = freqs[idx], g = gains[idx], Q = qs[idx];
    float w0 = 6.28318530717958648f * f / 44100.0f;
    float sw = sinf(w0), cw = cosf(w0);
    float alpha = sw / (2.0f * Q);
    float A = expf(g * 0.05756462732485114f);   // 10^(g/40)
    float aA = alpha * A, adA = alpha / A;
    float inv = 1.0f / (1.0f + adA);
    float c0 = (1.0f + aA) * inv;
    float c1 = -2.0f * cw * inv;
    float c2 = (1.0f - aA) * inv;
    float c3 = 2.0f * cw * inv;      // -a1
    float c4 = -(1.0f - adA) * inv;  // -a2
    cfs[tid*5+0] = c0; cfs[tid*5+1] = c1; cfs[tid*5+2] = c2;
    cfs[tid*5+3] = c3; cfs[tid*5+4] = c4;
    float* o = coef + idx * 5;
    o[0] = c0; o[1] = c1; o[2] = c2; o[3] = c3; o[4] = c4;
  }
  __syncthreads();
  if (tid < 20) {
    int c = tid;
    float rp = 0.0f;
    for (int k = 0; k < NB; k++) {
      float b0 = cfs[k*5+0], b1 = cfs[k*5+1], b2 = cfs[k*5+2];
      float na1 = cfs[k*5+3], na2 = cfs[k*5+4];
      float val = (k > 0) ? b0 * rp : 0.0f;
      if (k > 0) {
        if (c == 2*k-2) val += b1;
        if (c == 2*k-1) val += b2;
      }
      if (c == 2*k)   val += na1;
      if (c == 2*k+1) val += na2;
      bufA[2*k*20 + c] = val;
      rp = val;
      if (c == 2*k) bufA[(2*k+1)*20 + c] = 1.0f;
    }
  }
  __syncthreads();
  float* cur = bufA;
  float* nxt = bufB;
  float* pw = powers + (size_t)b * F_NPOW * 400;
  for (int j = 1; j <= 17; j++) {   // cur becomes A^(2^j)
    for (int e = tid; e < 400; e += 256) {
      int r = e / 20, c = e % 20;
      float acc = 0.0f;
      #pragma unroll
      for (int k = 0; k < 20; k++) acc = fmaf(cur[r*20+k], cur[k*20+c], acc);
      nxt[e] = acc;
    }
    __syncthreads();
    { float* t_ = cur; cur = nxt; nxt = t_; }
    int slot = -1;
    if (j == 6) slot = 0;            // A^64
    else if (j == 8) slot = 1;       // A^256 (layout only)
    else if (j == 9) slot = 2;       // A^512
    else if (j >= 10) slot = j - 7;  // A^1024..A^131072
    if (slot >= 0) for (int e = tid; e < 400; e += 256) pw[slot*400 + e] = cur[e];
  }
}

// ===========================================================================
// pass v4 helpers
// ===========================================================================
__device__ __forceinline__ void stage_tile(const float* xseq, float4* dst,
                                           int tile, int lane) {
  const float4* gx = (const float4*)(xseq + (size_t)tile * 4096);
  #pragma unroll
  for (int it = 0; it < 16; it++) {
    const int f = it * 64 + lane;
    const int c = f >> 4;
    const int gi = (c << 4) | ((f & 15) ^ (c & 15));
    __builtin_amdgcn_global_load_lds(
        (const __attribute__((address_space(1))) void*)(gx + gi),
        (__attribute__((address_space(3))) void*)(dst + it * 64),
        16, 0, 0);
  }
}

template <bool WRITE_OUT>
__device__ __forceinline__ void prefetch_es(
    const float* xseq, const float* tst, int seq, int tile, int lane,
    float2& pe, float4 (&pst)[5]) {
  if (tile > 0) {
    const float2* ep = (const float2*)(xseq + (size_t)tile * 4096) - 1;
    pe = *ep;                        // {x[-2], x[-1]} (same addr all lanes)
  } else {
    pe = make_float2(0.f, 0.f);
  }
  if constexpr (WRITE_OUT) {
    const int chunk = tile * F_LCH + lane;
    const int cm1 = chunk > 0 ? chunk - 1 : 0;   // clamp; zeroed later
    const int jj = cm1 & 7, gg = cm1 >> 3;
    const float4* sv = (const float4*)tst +
                       (((size_t)seq * 8 + jj) * 5) * 512 + gg;
    #pragma unroll
    for (int i = 0; i < 5; i++) pst[i] = sv[i * 512];
  }
}

// ===========================================================================
// passes: 1 wave per wg, NT tiles pipelined, no barriers.
// ===========================================================================
template <bool WRITE_OUT>
__global__ __launch_bounds__(64) void pass_v4(
    const float* __restrict__ x, const float* __restrict__ coef,
    const float* __restrict__ tst, float* __restrict__ tout,
    float* __restrict__ out) {
  __shared__ float4 lds4[2048];     // 2 x 16 KB double buffer
  const int seq = blockIdx.y;
  const int b = seq >> 1;
  const int lane = threadIdx.x;
  const int tile0 = blockIdx.x * NT;
  const float* cf = coef + b * NB * 5;       // uniform -> scalar loads
  float b0[NB], b1[NB], b2[NB], na1[NB], na2[NB];
  #pragma unroll
  for (int k = 0; k < NB; k++) {
    b0[k] = cf[k*5+0]; b1[k] = cf[k*5+1]; b2[k] = cf[k*5+2];
    na1[k] = cf[k*5+3]; na2[k] = cf[k*5+4];
  }
  const float* xseq = x + (size_t)seq * S_;

  float2 peC = make_float2(0.f, 0.f), peN = make_float2(0.f, 0.f);
  float4 pstC[5] = {}, pstN[5] = {};

  stage_tile(xseq, lds4, tile0, lane);
  prefetch_es<WRITE_OUT>(xseq, tst, seq, tile0, lane, peC, pstC);

  #pragma unroll 1
  for (int t = 0; t < NT; t++) {
    const int tile = tile0 + t;
    float4* lbuf = lds4 + ((t & 1) << 10);
    asm volatile("s_waitcnt vmcnt(0) lgkmcnt(0)" ::: "memory");
    __builtin_amdgcn_sched_barrier(0);
    if (t + 1 < NT) {   // overlap next tile's staging with this compute
      stage_tile(xseq, lds4 + (((t + 1) & 1) << 10), tile + 1, lane);
      prefetch_es<WRITE_OUT>(xseq, tst, seq, tile + 1, lane, peN, pstN);
    }
    // ---- init state ----
    const int chunk = tile * F_LCH + lane;
    float x1, x2;
    if (lane == 0) {
      x1 = peC.y; x2 = peC.x;       // zeros when tile==0
    } else {
      float4 pv = lbuf[(lane-1)*16 + (15 ^ ((lane-1) & 15))];
      x2 = pv.z; x1 = pv.w;
    }
    float p[NB], q_[NB];
    if (WRITE_OUT) {
      const bool z = (chunk == 0);
      #pragma unroll
      for (int i = 0; i < 5; i++) {
        float4 a = pstC[i];
        p[2*i]   = z ? 0.f : a.x;  q_[2*i]   = z ? 0.f : a.y;
        p[2*i+1] = z ? 0.f : a.z;  q_[2*i+1] = z ? 0.f : a.w;
      }
    } else {
      #pragma unroll
      for (int k = 0; k < NB; k++) { p[k] = 0.0f; q_[k] = 0.0f; }
    }
    // ---- compute: my chunk = lane, 16 float4 from LDS ----
    #pragma unroll 2
    for (int qq = 0; qq < 16; qq++) {
      const int slot = lane*16 + (qq ^ (lane & 15));
      float4 xv = lbuf[slot];
      float xin[4] = {xv.x, xv.y, xv.z, xv.w};
      float o[4];
      #pragma unroll
      for (int j = 0; j < 4; j++) {
        float u = xin[j], u1 = x1, u2 = x2;
        x2 = x1; x1 = xin[j];
        #pragma unroll
        for (int k = 0; k < NB; k++) {
          float v = fmaf(b0[k], u,
                    fmaf(b1[k], u1,
                    fmaf(b2[k], u2,
                    fmaf(na1[k], p[k], na2[k] * q_[k]))));
          u1 = p[k]; u2 = q_[k];
          q_[k] = p[k]; p[k] = v;
          u = v;
        }
        o[j] = u;
      }
      if (WRITE_OUT) lbuf[slot] = make_float4(o[0], o[1], o[2], o[3]);
    }
    if (WRITE_OUT) {
      asm volatile("" ::: "memory");
      float4* gy = (float4*)(out + (size_t)seq * S_ + (size_t)tile * 4096);
      #pragma unroll 4
      for (int it = 0; it < 16; it++) {
        int f = it * 64 + lane;
        int c = f >> 4, q = f & 15;
        gy[f] = lbuf[c*16 + (q ^ (c & 15))];
      }
    } else {
      const int jj = chunk & 7, gg = chunk >> 3;
      float4* td = (float4*)tout + (((size_t)seq * 8 + jj) * 5) * 512 + gg;
      td[0]    = make_float4(p[0], q_[0], p[1], q_[1]);
      td[512]  = make_float4(p[2], q_[2], p[3], q_[3]);
      td[1024] = make_float4(p[4], q_[4], p[5], q_[5]);
      td[1536] = make_float4(p[6], q_[6], p[7], q_[7]);
      td[2048] = make_float4(p[8], q_[8], p[9], q_[9]);
    }
    peC = peN;
    #pragma unroll
    for (int i = 0; i < 5; i++) pstC[i] = pstN[i];
  }
}

// ===========================================================================
// shared matvec helper (M transposed in LDS: M[c*20+r])
// ===========================================================================
__device__ __forceinline__ void matvec_acc(const float* M,
                                           const float* v, float* acc) {
  #pragma unroll
  for (int c = 0; c < 20; c++) {
    float vc = v[c];
    const float4* col = (const float4*)&M[c*20];
    float4 c0 = col[0], c1 = col[1], c2 = col[2], c3 = col[3], c4 = col[4];
    acc[0]  = fmaf(c0.x, vc, acc[0]);  acc[1]  = fmaf(c0.y, vc, acc[1]);
    acc[2]  = fmaf(c0.z, vc, acc[2]);  acc[3]  = fmaf(c0.w, vc, acc[3]);
    acc[4]  = fmaf(c1.x, vc, acc[4]);  acc[5]  = fmaf(c1.y, vc, acc[5]);
    acc[6]  = fmaf(c1.z, vc, acc[6]);  acc[7]  = fmaf(c1.w, vc, acc[7]);
    acc[8]  = fmaf(c2.x, vc, acc[8]);  acc[9]  = fmaf(c2.y, vc, acc[9]);
    acc[10] = fmaf(c2.z, vc, acc[10]); acc[11] = fmaf(c2.w, vc, acc[11]);
    acc[12] = fmaf(c3.x, vc, acc[12]); acc[13] = fmaf(c3.y, vc, acc[13]);
    acc[14] = fmaf(c3.z, vc, acc[14]); acc[15] = fmaf(c3.w, vc, acc[15]);
    acc[16] = fmaf(c4.x, vc, acc[16]); acc[17] = fmaf(c4.y, vc, acc[17]);
    acc[18] = fmaf(c4.z, vc, acc[18]); acc[19] = fmaf(c4.w, vc, acc[19]);
  }
}

// ===========================================================================
// scan phase 1/3: per-group Horner walk with A^64. 128-thread WGs, grid 4x64
// = 256 WGs (all CUs), VGPR cap 256 -> no spills. Transposed-T coalesced.
// ===========================================================================
template <bool WRITE_BACK>
__global__ __launch_bounds__(128) void scan_horner(
    float* __restrict__ t, const float* __restrict__ powers,
    float* __restrict__ gbuf, const float* __restrict__ sbuf) {
  __shared__ float Msh[400];        // Msh[c*20+r] = M[r][c]
  const int seq = blockIdx.y, b = seq >> 1;
  const int g = blockIdx.x * 128 + threadIdx.x;   // 0..511
  const float* pw0 = powers + (size_t)b * F_NPOW * 400;
  for (int e = threadIdx.x; e < 400; e += 128) {
    int r = e / 20, c = e % 20;
    Msh[c*20 + r] = pw0[e];
  }
  __syncthreads();
  float s[20];
  if (WRITE_BACK) {
    const float4* sv = (const float4*)(sbuf + ((size_t)seq * F_GRP + g) * 20);
    #pragma unroll
    for (int i = 0; i < 5; i++) {
      float4 a = sv[i];
      s[4*i] = a.x; s[4*i+1] = a.y; s[4*i+2] = a.z; s[4*i+3] = a.w;
    }
  } else {
    #pragma unroll
    for (int r = 0; r < 20; r++) s[r] = 0.0f;
  }
  const float4* tb = (const float4*)t + (size_t)seq * 40 * 512 + g;
  float4* tw = (float4*)t + (size_t)seq * 40 * 512 + g;
  float4 nx[5];
  #pragma unroll
  for (int i = 0; i < 5; i++) nx[i] = tb[i * 512];        // j=0
  #pragma unroll 1
  for (int j = 0; j < F_G; j++) {
    float ns[20];
    #pragma unroll
    for (int i = 0; i < 5; i++) {
      float4 a = nx[i];
      ns[4*i] = a.x; ns[4*i+1] = a.y; ns[4*i+2] = a.z; ns[4*i+3] = a.w;
    }
    if (j < F_G - 1) {
      const float4* np = tb + (size_t)(j + 1) * 5 * 512;
      #pragma unroll
      for (int i = 0; i < 5; i++) nx[i] = np[i * 512];    // prefetch next
    }
    matvec_acc(Msh, s, ns);
    #pragma unroll
    for (int r = 0; r < 20; r++) s[r] = ns[r];
    if (WRITE_BACK) {
      float4* wp = tw + (size_t)j * 5 * 512;
      wp[0]    = make_float4(s[0],  s[1],  s[2],  s[3]);
      wp[512]  = make_float4(s[4],  s[5],  s[6],  s[7]);
      wp[1024] = make_float4(s[8],  s[9],  s[10], s[11]);
      wp[1536] = make_float4(s[12], s[13], s[14], s[15]);
      wp[2048] = make_float4(s[16], s[17], s[18], s[19]);
    }
  }
  if (!WRITE_BACK) {
    float4* gw = (float4*)(gbuf + ((size_t)seq * F_GRP + g) * 20);
    #pragma unroll
    for (int i = 0; i < 5; i++)
      gw[i] = make_float4(s[4*i], s[4*i+1], s[4*i+2], s[4*i+3]);
  }
}

// ===========================================================================
// scan phase 2: Kogge-Stone over 512 group totals, one wg per sequence
// (verbatim from validated round 3)
// ===========================================================================
__global__ __launch_bounds__(512) void scan_ks(
    const float* __restrict__ gbuf, const float* __restrict__ powers,
    float* __restrict__ sbuf) {
  __shared__ float h[F_GRP * 20];   // 40 KB
  __shared__ float Ksh[400];        // transposed step matrix
  const int seq = blockIdx.x, b = seq >> 1, i = threadIdx.x;
  const float* pw = powers + (size_t)b * F_NPOW * 400;
  float own[20];
  {
    const float4* gv = (const float4*)(gbuf + ((size_t)seq * F_GRP + i) * 20);
    #pragma unroll
    for (int k = 0; k < 5; k++) {
      float4 a = gv[k];
      own[4*k] = a.x; own[4*k+1] = a.y; own[4*k+2] = a.z; own[4*k+3] = a.w;
    }
  }
  #pragma unroll
  for (int r = 0; r < 20; r++) h[i*20 + r] = own[r];
  for (int s = 0; s < 9; s++) {     // distances 1..256 groups
    const int d = 1 << s;
    const float* pwS = pw + (size_t)(2 + s) * 400;   // A^(512*2^s)
    __syncthreads();
    for (int e = i; e < 400; e += 512) {
      int r = e / 20, c = e % 20;
      Ksh[c*20 + r] = pwS[e];
    }
    float nb[20];
    if (i >= d) {
      const float4* hv = (const float4*)&h[(i - d) * 20];
      #pragma unroll
      for (int k = 0; k < 5; k++) {
        float4 a = hv[k];
        nb[4*k] = a.x; nb[4*k+1] = a.y; nb[4*k+2] = a.z; nb[4*k+3] = a.w;
      }
    }
    __syncthreads();
    if (i >= d) {
      matvec_acc(Ksh, nb, own);
      #pragma unroll
      for (int r = 0; r < 20; r++) h[i*20 + r] = own[r];
    }
  }
  __syncthreads();
  float4* sw = (float4*)(sbuf + ((size_t)seq * F_GRP + i) * 20);
  if (i > 0) {
    const float4* hv = (const float4*)&h[(i - 1) * 20];
    #pragma unroll
    for (int k = 0; k < 5; k++) sw[k] = hv[k];
  } else {
    #pragma unroll
    for (int k = 0; k < 5; k++) sw[k] = make_float4(0.f, 0.f, 0.f, 0.f);
  }
}

// ===========================================================================
extern "C" void kernel_launch(void* const* d_in, const int* in_sizes, int n_in,
                              void* d_out, int out_size, void* d_ws, size_t ws_size,
                              hipStream_t stream) {
  const float* audio = (const float*)d_in[0];
  const float* freqs = (const float*)d_in[1];
  const float* gains = (const float*)d_in[2];
  const float* qs    = (const float*)d_in[3];
  float* out = (float*)d_out;
  float* ws  = (float*)d_ws;
  float* coef   = ws;
  float* powers = ws + F_OFF_POW;
  float* t      = ws + F_OFF_T;
  float* gbuf   = ws + F_OFF_G;
  float* sbuf   = ws + F_OFF_SB;

  hipLaunchKernelGGL(setup_kernel, dim3(B_), dim3(256), 0, stream,
                     freqs, gains, qs, coef, powers);
  hipLaunchKernelGGL((pass_v4<false>), dim3(64 / NT, SEQ), dim3(64), 0, stream,
                     audio, coef, (const float*)nullptr, t, (float*)nullptr);
  hipLaunchKernelGGL((scan_horner<false>), dim3(F_GRP / 128, SEQ), dim3(128),
                     0, stream, t, powers, gbuf, (const float*)nullptr);
  hipLaunchKernelGGL(scan_ks, dim3(SEQ), dim3(512), 0, stream,
                     gbuf, powers, sbuf);
  hipLaunchKernelGGL((scan_horner<true>), dim3(F_GRP / 128, SEQ), dim3(128),
                     0, stream, t, powers, (float*)nullptr, sbuf);
  hipLaunchKernelGGL((pass_v4<true>), dim3(64 / NT, SEQ), dim3(64), 0, stream,
                     audio, coef, t, (float*)nullptr, out);
}

// Round 4
// 263.728 us; speedup vs baseline: 1.9740x; 1.0073x over previous
//
#include <hip/hip_runtime.h>

// ---------------------------------------------------------------------------
// SimpleBiquadEQ: 10-band peaking-EQ cascade (IIR) over [32,2,262144] fp32.
// Round 7:
//  - Passes revert to proven high-TLP structure: 4096 single-wave WGs, ONE
//    16 KB tile each (r3's 45 µs config), global_load_lds staging.
//  - FUSE the group scans into the passes via in-wave segmented Kogge-Stone
//    (segments = 8 aligned lanes = one scan group of 8 chunks):
//      * pass<false>: after the filter, T_c is in registers; 3 masked KS
//        steps (A^64/A^128/A^256 uniform from LDS) produce the group total;
//        lane c&7==7 writes gbuf. horner<false> ELIMINATED.
//      * pass<true>: w_c = (c&7==0 ? sbuf[g] : T_{c-1}); same 3 KS steps
//        compute s_c (exact rewalk recurrence) per lane. horner<true> and
//        its 42 MB T round-trip ELIMINATED.
//  - setup: adds A^128; slots 0..2 (A^64/128/256) stored COL-major for the
//    pass-side matvec; KS slots 3..11 row-major as before.
//  - scan_ks unchanged except power-slot base 2 -> 3.
//  - 6 launches -> 4.
// ---------------------------------------------------------------------------

#define B_   32
#define C_   2
#define S_   262144
#define NB   10
#define SEQ  64

#define F_LCH   64          // samples per chunk
#define F_PCH   4096        // chunks per sequence
#define F_G     8           // chunks per scan group
#define F_GRP   512         // groups per sequence
#define F_NPOW  12          // 0=A^64(T) 1=A^128(T) 2=A^256(T) 3..11=A^(512*2^s)

// ws layout (floats)
#define F_OFF_POW 1600
#define F_OFF_T   155200            // 1600 + 32*12*400
#define F_OFF_G   5398080           // + 64*4096*20
#define F_OFF_SB  6053440           // + 64*512*20
#define F_TOT     6708800           // 26.8 MB

// T addressing (float4 units): plane(seq,j,i) = ((seq*8 + j)*5 + i)*512, + g
// where chunk = 8*g + j.

// ===========================================================================
// setup: coefficients + matrix powers
// ===========================================================================
__global__ __launch_bounds__(256) void setup_kernel(
    const float* __restrict__ freqs, const float* __restrict__ gains,
    const float* __restrict__ qs, float* __restrict__ coef,
    float* __restrict__ powers) {
  __shared__ float bufA[400], bufB[400];
  __shared__ float cfs[NB * 5];
  const int b = blockIdx.x, tid = threadIdx.x;
  for (int e = tid; e < 400; e += 256) bufA[e] = 0.0f;
  if (tid < NB) {
    int idx = b * NB + tid;
    float f = freqs[idx], g = gains[idx], Q = qs[idx];
    float w0 = 6.28318530717958648f * f / 44100.0f;
    float sw = sinf(w0), cw = cosf(w0);
    float alpha = sw / (2.0f * Q);
    float A = expf(g * 0.05756462732485114f);   // 10^(g/40)
    float aA = alpha * A, adA = alpha / A;
    float inv = 1.0f / (1.0f + adA);
    float c0 = (1.0f + aA) * inv;
    float c1 = -2.0f * cw * inv;
    float c2 = (1.0f - aA) * inv;
    float c3 = 2.0f * cw * inv;      // -a1
    float c4 = -(1.0f - adA) * inv;  // -a2
    cfs[tid*5+0] = c0; cfs[tid*5+1] = c1; cfs[tid*5+2] = c2;
    cfs[tid*5+3] = c3; cfs[tid*5+4] = c4;
    float* o = coef + idx * 5;
    o[0] = c0; o[1] = c1; o[2] = c2; o[3] = c3; o[4] = c4;
  }
  __syncthreads();
  if (tid < 20) {
    int c = tid;
    float rp = 0.0f;
    for (int k = 0; k < NB; k++) {
      float b0 = cfs[k*5+0], b1 = cfs[k*5+1], b2 = cfs[k*5+2];
      float na1 = cfs[k*5+3], na2 = cfs[k*5+4];
      float val = (k > 0) ? b0 * rp : 0.0f;
      if (k > 0) {
        if (c == 2*k-2) val += b1;
        if (c == 2*k-1) val += b2;
      }
      if (c == 2*k)   val += na1;
      if (c == 2*k+1) val += na2;
      bufA[2*k*20 + c] = val;
      rp = val;
      if (c == 2*k) bufA[(2*k+1)*20 + c] = 1.0f;
    }
  }
  __syncthreads();
  float* cur = bufA;
  float* nxt = bufB;
  float* pw = powers + (size_t)b * F_NPOW * 400;
  for (int j = 1; j <= 17; j++) {   // cur becomes A^(2^j)
    for (int e = tid; e < 400; e += 256) {
      int r = e / 20, c = e % 20;
      float acc = 0.0f;
      #pragma unroll
      for (int k = 0; k < 20; k++) acc = fmaf(cur[r*20+k], cur[k*20+c], acc);
      nxt[e] = acc;
    }
    __syncthreads();
    { float* t_ = cur; cur = nxt; nxt = t_; }
    int slot = -1;
    if (j == 6) slot = 0;            // A^64
    else if (j == 7) slot = 1;       // A^128
    else if (j == 8) slot = 2;       // A^256
    else if (j >= 9) slot = j - 6;   // 3..11 = A^512 .. A^131072
    if (slot >= 0) {
      if (slot < 3) {
        for (int e = tid; e < 400; e += 256)
          pw[slot*400 + (e % 20) * 20 + e / 20] = cur[e];   // col-major
      } else {
        for (int e = tid; e < 400; e += 256)
          pw[slot*400 + e] = cur[e];                         // row-major
      }
    }
  }
}

// ===========================================================================
// shared matvec helper (M col-major: M[c*20+r]); acc += M*v
// ===========================================================================
__device__ __forceinline__ void matvec_acc(const float* M,
                                           const float* v, float* acc) {
  #pragma unroll
  for (int c = 0; c < 20; c++) {
    float vc = v[c];
    const float4* col = (const float4*)&M[c*20];
    float4 c0 = col[0], c1 = col[1], c2 = col[2], c3 = col[3], c4 = col[4];
    acc[0]  = fmaf(c0.x, vc, acc[0]);  acc[1]  = fmaf(c0.y, vc, acc[1]);
    acc[2]  = fmaf(c0.z, vc, acc[2]);  acc[3]  = fmaf(c0.w, vc, acc[3]);
    acc[4]  = fmaf(c1.x, vc, acc[4]);  acc[5]  = fmaf(c1.y, vc, acc[5]);
    acc[6]  = fmaf(c1.z, vc, acc[6]);  acc[7]  = fmaf(c1.w, vc, acc[7]);
    acc[8]  = fmaf(c2.x, vc, acc[8]);  acc[9]  = fmaf(c2.y, vc, acc[9]);
    acc[10] = fmaf(c2.z, vc, acc[10]); acc[11] = fmaf(c2.w, vc, acc[11]);
    acc[12] = fmaf(c3.x, vc, acc[12]); acc[13] = fmaf(c3.y, vc, acc[13]);
    acc[14] = fmaf(c3.z, vc, acc[14]); acc[15] = fmaf(c3.w, vc, acc[15]);
    acc[16] = fmaf(c4.x, vc, acc[16]); acc[17] = fmaf(c4.y, vc, acc[17]);
    acc[18] = fmaf(c4.z, vc, acc[18]); acc[19] = fmaf(c4.w, vc, acc[19]);
  }
}

// one masked Kogge-Stone step over 8-lane segments: s += M * s[lane-d]
// (only where (lane&7) >= d)
__device__ __forceinline__ void ks_step(float* s, const float* M, int d,
                                        int lanem) {
  float t[20];
  #pragma unroll
  for (int r = 0; r < 20; r++) t[r] = __shfl_up(s[r], d, 64);
  float ns[20];
  #pragma unroll
  for (int r = 0; r < 20; r++) ns[r] = s[r];
  matvec_acc(M, t, ns);
  const bool c = (lanem >= d);
  #pragma unroll
  for (int r = 0; r < 20; r++) s[r] = c ? ns[r] : s[r];
}

// ===========================================================================
// passes: 1 wave per wg, one 16 KB tile, in-wave group scans fused.
// LDS: 1024 float4 tile + 320 float4 (A^64,A^128,A^256 col-major + pad)
// ===========================================================================
template <bool WRITE_OUT>
__global__ __launch_bounds__(64) void pass_v5(
    const float* __restrict__ x, const float* __restrict__ coef,
    const float* __restrict__ powers, float* __restrict__ t,
    float* __restrict__ aux,   // <false>: gbuf (write) ; <true>: sbuf (read)
    float* __restrict__ out) {
  __shared__ float4 smem[1024 + 320];
  const int seq = blockIdx.y;
  const int b = seq >> 1;
  const int lane = threadIdx.x;
  const int lanem = lane & 7;
  const int tile = blockIdx.x;               // 0..63
  const int chunk = tile * F_LCH + lane;     // seq-local chunk id
  const float* cf = coef + b * NB * 5;       // uniform -> scalar loads
  float b0[NB], b1[NB], b2[NB], na1[NB], na2[NB];
  #pragma unroll
  for (int k = 0; k < NB; k++) {
    b0[k] = cf[k*5+0]; b1[k] = cf[k*5+1]; b2[k] = cf[k*5+2];
    na1[k] = cf[k*5+3]; na2[k] = cf[k*5+4];
  }
  const float* xseq = x + (size_t)seq * S_;

  // ---- stage matrices: 320 float4 from powers (slots 0..2 col-major) ----
  const float4* pwv4 = (const float4*)(powers + (size_t)b * F_NPOW * 400);
  #pragma unroll
  for (int it = 0; it < 5; it++) {
    __builtin_amdgcn_global_load_lds(
        (const __attribute__((address_space(1))) void*)(pwv4 + it * 64 + lane),
        (__attribute__((address_space(3))) void*)(smem + 1024 + it * 64),
        16, 0, 0);
  }
  // ---- stage tile: pre-swizzled global source, linear LDS dest ----
  {
    const float4* gx = (const float4*)(xseq + (size_t)tile * 4096);
    #pragma unroll
    for (int it = 0; it < 16; it++) {
      const int f = it * 64 + lane;
      const int c = f >> 4;
      const int gi = (c << 4) | ((f & 15) ^ (c & 15));
      __builtin_amdgcn_global_load_lds(
          (const __attribute__((address_space(1))) void*)(gx + gi),
          (__attribute__((address_space(3))) void*)(smem + it * 64),
          16, 0, 0);
    }
  }
  // ---- edge samples (x[-1], x[-2] of the tile) ----
  float2 pe = make_float2(0.f, 0.f);
  if (tile > 0) {
    const float2* ep = (const float2*)(xseq + (size_t)tile * 4096) - 1;
    pe = *ep;                        // same addr all lanes (broadcast)
  }
  // ---- <true>: load w-parts (T_{chunk-1} and sbuf[g]) early ----
  float4 tw4[5], sb4[5];
  if constexpr (WRITE_OUT) {
    const int cm1 = (chunk > 0) ? chunk - 1 : 0;
    const int jj = cm1 & 7, gg = cm1 >> 3;
    const float4* tvp = (const float4*)t + ((size_t)seq * 8 + jj) * 5 * 512 + gg;
    #pragma unroll
    for (int i = 0; i < 5; i++) tw4[i] = tvp[i * 512];
    const int g = chunk >> 3;
    const float4* sv = (const float4*)(aux + ((size_t)seq * F_GRP + g) * 20);
    #pragma unroll
    for (int i = 0; i < 5; i++) sb4[i] = sv[i];
  }

  asm volatile("s_waitcnt vmcnt(0) lgkmcnt(0)" ::: "memory");
  __builtin_amdgcn_sched_barrier(0);

  const float* M1 = (const float*)(smem + 1024);         // A^64  col-major
  const float* M2 = (const float*)(smem + 1024) + 400;   // A^128
  const float* M4 = (const float*)(smem + 1024) + 800;   // A^256

  // ---- init filter state ----
  float p[NB], q_[NB];
  if constexpr (WRITE_OUT) {
    // w_c = (lanem==0 ? sbuf[g] : T_{chunk-1}); inclusive segmented KS
    // over 8-lane segments with combine s' = A^64*s + w  ==> w becomes s_c.
    float w[20];
    const bool useS = (lanem == 0);
    #pragma unroll
    for (int i = 0; i < 5; i++) {
      float4 a = useS ? sb4[i] : tw4[i];
      w[4*i] = a.x; w[4*i+1] = a.y; w[4*i+2] = a.z; w[4*i+3] = a.w;
    }
    ks_step(w, M1, 1, lanem);
    ks_step(w, M2, 2, lanem);
    ks_step(w, M4, 4, lanem);
    #pragma unroll
    for (int k = 0; k < NB; k++) { p[k] = w[2*k]; q_[k] = w[2*k+1]; }
  } else {
    #pragma unroll
    for (int k = 0; k < NB; k++) { p[k] = 0.0f; q_[k] = 0.0f; }
  }
  // ---- x1/x2 init from neighbor chunk in LDS ----
  float x1, x2;
  if (lane == 0) {
    x1 = pe.y; x2 = pe.x;            // zeros when tile==0
  } else {
    float4 pv = smem[(lane-1)*16 + (15 ^ ((lane-1) & 15))];
    x2 = pv.z; x1 = pv.w;
  }
  // ---- filter: my chunk = lane, 16 float4 from LDS ----
  #pragma unroll 2
  for (int qq = 0; qq < 16; qq++) {
    const int slot = lane*16 + (qq ^ (lane & 15));
    float4 xv = smem[slot];
    float xin[4] = {xv.x, xv.y, xv.z, xv.w};
    float o[4];
    #pragma unroll
    for (int j = 0; j < 4; j++) {
      float u = xin[j], u1 = x1, u2 = x2;
      x2 = x1; x1 = xin[j];
      #pragma unroll
      for (int k = 0; k < NB; k++) {
        float v = fmaf(b0[k], u,
                  fmaf(b1[k], u1,
                  fmaf(b2[k], u2,
                  fmaf(na1[k], p[k], na2[k] * q_[k]))));
        u1 = p[k]; u2 = q_[k];
        q_[k] = p[k]; p[k] = v;
        u = v;
      }
      o[j] = u;
    }
    if (WRITE_OUT) smem[slot] = make_float4(o[0], o[1], o[2], o[3]);
  }
  if constexpr (WRITE_OUT) {
    asm volatile("" ::: "memory");   // keep ds_writes before store-phase reads
    float4* gy = (float4*)(out + (size_t)seq * S_ + (size_t)tile * 4096);
    #pragma unroll 4
    for (int it = 0; it < 16; it++) {
      int f = it * 64 + lane;
      int c = f >> 4, q = f & 15;
      gy[f] = smem[c*16 + (q ^ (c & 15))];
    }
  } else {
    // ---- T write (transposed planes) ----
    const int jj = chunk & 7, gg = chunk >> 3;
    float4* td = (float4*)t + ((size_t)seq * 8 + jj) * 5 * 512 + gg;
    td[0]    = make_float4(p[0], q_[0], p[1], q_[1]);
    td[512]  = make_float4(p[2], q_[2], p[3], q_[3]);
    td[1024] = make_float4(p[4], q_[4], p[5], q_[5]);
    td[1536] = make_float4(p[6], q_[6], p[7], q_[7]);
    td[2048] = make_float4(p[8], q_[8], p[9], q_[9]);
    // ---- in-wave group total: inclusive segmented KS over T_c ----
    float s[20];
    #pragma unroll
    for (int k = 0; k < NB; k++) { s[2*k] = p[k]; s[2*k+1] = q_[k]; }
    ks_step(s, M1, 1, lanem);
    ks_step(s, M2, 2, lanem);
    ks_step(s, M4, 4, lanem);
    if (lanem == 7) {
      const int g = chunk >> 3;
      float4* gw = (float4*)(aux + ((size_t)seq * F_GRP + g) * 20);
      gw[0] = make_float4(s[0],  s[1],  s[2],  s[3]);
      gw[1] = make_float4(s[4],  s[5],  s[6],  s[7]);
      gw[2] = make_float4(s[8],  s[9],  s[10], s[11]);
      gw[3] = make_float4(s[12], s[13], s[14], s[15]);
      gw[4] = make_float4(s[16], s[17], s[18], s[19]);
    }
  }
}

// ===========================================================================
// scan phase 2: Kogge-Stone over 512 group totals, one wg per sequence
// (validated; power-slot base now 3)
// ===========================================================================
__global__ __launch_bounds__(512) void scan_ks(
    const float* __restrict__ gbuf, const float* __restrict__ powers,
    float* __restrict__ sbuf) {
  __shared__ float h[F_GRP * 20];   // 40 KB
  __shared__ float Ksh[400];        // transposed step matrix
  const int seq = blockIdx.x, b = seq >> 1, i = threadIdx.x;
  const float* pw = powers + (size_t)b * F_NPOW * 400;
  float own[20];
  {
    const float4* gv = (const float4*)(gbuf + ((size_t)seq * F_GRP + i) * 20);
    #pragma unroll
    for (int k = 0; k < 5; k++) {
      float4 a = gv[k];
      own[4*k] = a.x; own[4*k+1] = a.y; own[4*k+2] = a.z; own[4*k+3] = a.w;
    }
  }
  #pragma unroll
  for (int r = 0; r < 20; r++) h[i*20 + r] = own[r];
  for (int s = 0; s < 9; s++) {     // distances 1..256 groups
    const int d = 1 << s;
    const float* pwS = pw + (size_t)(3 + s) * 400;   // A^(512*2^s)
    __syncthreads();
    for (int e = i; e < 400; e += 512) {
      int r = e / 20, c = e % 20;
      Ksh[c*20 + r] = pwS[e];
    }
    float nb[20];
    if (i >= d) {
      const float4* hv = (const float4*)&h[(i - d) * 20];
      #pragma unroll
      for (int k = 0; k < 5; k++) {
        float4 a = hv[k];
        nb[4*k] = a.x; nb[4*k+1] = a.y; nb[4*k+2] = a.z; nb[4*k+3] = a.w;
      }
    }
    __syncthreads();
    if (i >= d) {
      matvec_acc(Ksh, nb, own);
      #pragma unroll
      for (int r = 0; r < 20; r++) h[i*20 + r] = own[r];
    }
  }
  __syncthreads();
  float4* sw = (float4*)(sbuf + ((size_t)seq * F_GRP + i) * 20);
  if (i > 0) {
    const float4* hv = (const float4*)&h[(i - 1) * 20];
    #pragma unroll
    for (int k = 0; k < 5; k++) sw[k] = hv[k];
  } else {
    #pragma unroll
    for (int k = 0; k < 5; k++) sw[k] = make_float4(0.f, 0.f, 0.f, 0.f);
  }
}

// ===========================================================================
extern "C" void kernel_launch(void* const* d_in, const int* in_sizes, int n_in,
                              void* d_out, int out_size, void* d_ws, size_t ws_size,
                              hipStream_t stream) {
  const float* audio = (const float*)d_in[0];
  const float* freqs = (const float*)d_in[1];
  const float* gains = (const float*)d_in[2];
  const float* qs    = (const float*)d_in[3];
  float* out = (float*)d_out;
  float* ws  = (float*)d_ws;
  float* coef   = ws;
  float* powers = ws + F_OFF_POW;
  float* t      = ws + F_OFF_T;
  float* gbuf   = ws + F_OFF_G;
  float* sbuf   = ws + F_OFF_SB;

  hipLaunchKernelGGL(setup_kernel, dim3(B_), dim3(256), 0, stream,
                     freqs, gains, qs, coef, powers);
  hipLaunchKernelGGL((pass_v5<false>), dim3(F_PCH / F_LCH, SEQ), dim3(64), 0,
                     stream, audio, coef, powers, t, gbuf, (float*)nullptr);
  hipLaunchKernelGGL(scan_ks, dim3(SEQ), dim3(512), 0, stream,
                     gbuf, powers, sbuf);
  hipLaunchKernelGGL((pass_v5<true>), dim3(F_PCH / F_LCH, SEQ), dim3(64), 0,
                     stream, audio, coef, powers, t, sbuf, out);
}